// Round 15
// baseline (180.888 us; speedup 1.0000x reference)
//
#include <hip/hip_runtime.h>
#include <hip/hip_bf16.h>
#include <stdint.h>

typedef __attribute__((ext_vector_type(8))) __bf16 bf16x8;
typedef __attribute__((ext_vector_type(8))) unsigned short ushort8_t;
typedef __attribute__((ext_vector_type(4))) unsigned short ushort4_t;
typedef __attribute__((ext_vector_type(4))) float f32x4;

#define MFMA16(a, b, c) __builtin_amdgcn_mfma_f32_16x16x32_bf16((a), (b), (c), 0, 0, 0)

static __device__ __forceinline__ unsigned short f2bf(float f) {
  union { float f; unsigned u; } v; v.f = f;
  unsigned r = v.u + 0x7fffu + ((v.u >> 16) & 1u);  // RNE
  return (unsigned short)(r >> 16);
}
static __device__ __forceinline__ float bf2f(unsigned short u) {
  union { unsigned u; float f; } v; v.u = ((unsigned)u) << 16; return v.f;
}

static __device__ __forceinline__ void gld_lds16(const void* g, void* l) {
  __builtin_amdgcn_global_load_lds((const __attribute__((address_space(1))) void*)g,
                                   (__attribute__((address_space(3))) void*)l, 16, 0, 0);
}

// ---------------- kernel 0: convert x, w_qkv, w_out f32 -> bf16 (grid-stride, one launch)
__global__ __launch_bounds__(256) void k_conv(const float* __restrict__ x,
                                              const float* __restrict__ wqkv,
                                              const float* __restrict__ wout,
                                              unsigned short* __restrict__ xb,
                                              unsigned short* __restrict__ wqb,
                                              unsigned short* __restrict__ woutb) {
  const size_t NX = 4194304;   // 65536*256/4
  const size_t NW = 98304;     // 1536*256/4
  const size_t NO = 32768;     // 256*512/4
  const size_t stride = (size_t)gridDim.x * 256;
  for (size_t i4 = (size_t)blockIdx.x * 256 + threadIdx.x; i4 < NX + NW + NO; i4 += stride) {
    const float* src; unsigned short* dst; size_t off;
    if (i4 < NX)           { src = x;    dst = xb;    off = i4; }
    else if (i4 < NX + NW) { src = wqkv; dst = wqb;   off = i4 - NX; }
    else                   { src = wout; dst = woutb; off = i4 - NX - NW; }
    float4 v = ((const float4*)src)[off];
    ushort4_t o = { f2bf(v.x), f2bf(v.y), f2bf(v.z), f2bf(v.w) };
    *(ushort4_t*)(dst + off * 4) = o;
  }
}

// ---------------- kernel 1: FUSED K/V projection + instance-norm + dots.  v7 =
// round-8 base + (1) ktt0 B-fragments in registers (loaded once per block; prologue
// B-staging and ktt0 B-LDS-reads removed), (2) swizzled [64][64] overlay housed in
// the Bs dbuf region, (3) setprio around MFMA clusters. Dataflow otherwise identical.
__global__ __launch_bounds__(512) void k_fused(const unsigned short* __restrict__ xb,
                                               const unsigned short* __restrict__ wqb,
                                               float* __restrict__ partials) {
  __shared__ __align__(16) char smem[65536];
  unsigned short* As = (unsigned short*)smem;             // [2][128*64] = 32 KB
  unsigned short* Bs = (unsigned short*)(smem + 32768);   // [2][128*64] = 32 KB
  unsigned short* kt = (unsigned short*)(smem + 32768);   // overlay in Bs buf0 (16 KB)
  unsigned short* vt = (unsigned short*)(smem + 49152);   // overlay in Bs buf1 (16 KB)

  const int t = threadIdx.x;
  const int w = t >> 6, lane = t & 63, lr = lane & 15, lg = lane >> 4;
  const int wr = w >> 1, wc = w & 1;    // GEMM: 32-row strip wr, tensor wc (0=K,1=V)
  const int dblk = w >> 1, ep = w & 1;  // dots role: d-block, e-half

  // XCD-chunked swizzle: 1024 blocks = 128 mgroups x 8 heads; XCD owns 16 mgroups
  const int id = blockIdx.x;
  const int nid = (id & 7) * 128 + (id >> 3);
  const int mg = nid >> 3, h = nid & 7;

  const int srl = lane >> 3, sc = lane & 7;
  const int swz = (sc ^ srl) << 3;      // staging row%8 == srl

  const unsigned short* bptr[2];
  int aoff[2];
#pragma unroll
  for (int i = 0; i < 2; ++i) {
    const int br = (w * 2 + i) * 8 + srl;   // 0..127
    const int grow = (br < 64) ? (512 + h * 64 + br) : (1024 + h * 64 + (br - 64));
    bptr[i] = wqb + (size_t)grow * 256 + swz;
    aoff[i] = br * 256 + swz;
  }

  // ---- ktt0 B fragments: global -> regs, once per block (L2-hot weights)
  const int ebase = (wc == 0 ? 512 : 1024) + h * 64;
  const unsigned short* bgp = wqb + (size_t)(ebase + lr) * 256 + lg * 8;
  bf16x8 breg[2][4];  // [kh][nb]
#pragma unroll
  for (int kh = 0; kh < 2; ++kh)
#pragma unroll
    for (int nb = 0; nb < 4; ++nb)
      breg[kh][nb] = *(const bf16x8*)(bgp + (size_t)(nb * 16) * 256 + kh * 32);

  f32x4 acc2[2] = {f32x4{0.f, 0.f, 0.f, 0.f}, f32x4{0.f, 0.f, 0.f, 0.f}};

  for (int mi = 0; mi < 4; ++mi) {
    const unsigned short* am = xb + ((size_t)(mg * 4 + mi) * 128) * 256;

    // prologue: stage A K-step 0 only (B ktt0 is in regs)
#pragma unroll
    for (int i = 0; i < 2; ++i)
      gld_lds16(am + aoff[i], &As[(w * 2 + i) * 512]);
    __syncthreads();

    f32x4 acc[2][4];
#pragma unroll
    for (int mb = 0; mb < 2; ++mb)
#pragma unroll
      for (int nb = 0; nb < 4; ++nb) acc[mb][nb] = f32x4{0.f, 0.f, 0.f, 0.f};

#pragma unroll
    for (int ktt = 0; ktt < 4; ++ktt) {
      const int cur = ktt & 1, nxt = cur ^ 1;
      if (ktt < 3) {
        const int k0 = (ktt + 1) * 64;
#pragma unroll
        for (int i = 0; i < 2; ++i) {
          gld_lds16(am + aoff[i] + k0, &As[nxt * 8192 + (w * 2 + i) * 512]);
          gld_lds16(bptr[i] + k0,      &Bs[nxt * 8192 + (w * 2 + i) * 512]);
        }
      }
      bf16x8 a[2][2], b[4][2];
#pragma unroll
      for (int mb = 0; mb < 2; ++mb) {
        const int R = wr * 32 + mb * 16 + lr;
#pragma unroll
        for (int kh = 0; kh < 2; ++kh)
          a[mb][kh] = *(const bf16x8*)&As[cur * 8192 + R * 64 + ((((kh << 2) + lg) ^ (R & 7)) << 3)];
      }
      if (ktt == 0) {
#pragma unroll
        for (int nb = 0; nb < 4; ++nb)
#pragma unroll
          for (int kh = 0; kh < 2; ++kh)
            b[nb][kh] = breg[kh][nb];
      } else {
#pragma unroll
        for (int nb = 0; nb < 4; ++nb) {
          const int E = wc * 64 + nb * 16 + lr;
#pragma unroll
          for (int kh = 0; kh < 2; ++kh)
            b[nb][kh] = *(const bf16x8*)&Bs[cur * 8192 + E * 64 + ((((kh << 2) + lg) ^ (E & 7)) << 3)];
        }
      }
      __builtin_amdgcn_s_setprio(1);
#pragma unroll
      for (int mb = 0; mb < 2; ++mb)
#pragma unroll
        for (int nb = 0; nb < 4; ++nb)
#pragma unroll
          for (int kh = 0; kh < 2; ++kh)
            acc[mb][nb] = MFMA16(a[mb][kh], b[nb][kh], acc[mb][nb]);
      __builtin_amdgcn_s_setprio(0);
      __syncthreads();
    }

    // ---- instance-norm in-register, write into XOR-swizzled overlay (Bs region;
    // safe: ktt3's barrier retired all Bs reads; next staging into Bs happens
    // only after the next m-tile's prologue __syncthreads)
    unsigned short* dst = (wc == 0) ? kt : vt;
#pragma unroll
    for (int mb = 0; mb < 2; ++mb) {
#pragma unroll
      for (int rg = 0; rg < 4; ++rg) {
        float s1 = acc[mb][0][rg] + acc[mb][1][rg] + acc[mb][2][rg] + acc[mb][3][rg];
        float s2 = acc[mb][0][rg] * acc[mb][0][rg] + acc[mb][1][rg] * acc[mb][1][rg] +
                   acc[mb][2][rg] * acc[mb][2][rg] + acc[mb][3][rg] * acc[mb][3][rg];
        s1 += __shfl_xor(s1, 1); s2 += __shfl_xor(s2, 1);
        s1 += __shfl_xor(s1, 2); s2 += __shfl_xor(s2, 2);
        s1 += __shfl_xor(s1, 4); s2 += __shfl_xor(s2, 4);
        s1 += __shfl_xor(s1, 8); s2 += __shfl_xor(s2, 8);
        const float mean = s1 * (1.f / 64.f);
        const float rs = rsqrtf(s2 * (1.f / 64.f) - mean * mean + 1e-5f);
        const int n = wr * 32 + mb * 16 + lg * 4 + rg;
        const int cn = n >> 6, nn = n & 63;
        const int cc = nn >> 3, cj = nn & 7;
#pragma unroll
        for (int nb = 0; nb < 4; ++nb) {
          const int d = nb * 16 + lr;
          dst[cn * 4096 + d * 64 + ((cc ^ (d & 7)) << 3) + cj] =
              f2bf((acc[mb][nb][rg] - mean) * rs);
        }
      }
    }
    __syncthreads();

    // ---- dots: D[d,e] += sum_n K^[n,d] V^[n,e] (swizzled overlay reads)
    __builtin_amdgcn_s_setprio(1);
#pragma unroll
    for (int cn = 0; cn < 2; ++cn) {
#pragma unroll
      for (int ns = 0; ns < 64; ns += 32) {
        const int cA = (ns >> 3) + lg;
        const int dd = dblk * 16 + lr;
        bf16x8 af = *(const bf16x8*)&kt[cn * 4096 + dd * 64 + ((cA ^ (dd & 7)) << 3)];
#pragma unroll
        for (int e = 0; e < 2; ++e) {
          const int ee = (ep * 2 + e) * 16 + lr;
          bf16x8 bv = *(const bf16x8*)&vt[cn * 4096 + ee * 64 + ((cA ^ (ee & 7)) << 3)];
          acc2[e] = MFMA16(af, bv, acc2[e]);
        }
      }
    }
    __builtin_amdgcn_s_setprio(0);
    // no trailing barrier: next m-tile's prologue __syncthreads orders overlay
    // reads before any Bs re-staging (A prologue targets the As region only).
  }

  float* pb = partials + ((size_t)mg * 8 + h) * 4096;
#pragma unroll
  for (int e = 0; e < 2; ++e)
#pragma unroll
    for (int rg = 0; rg < 4; ++rg) {
      const int d = dblk * 16 + lg * 4 + rg;
      const int eo = (ep * 2 + e) * 16 + lr;
      pb[d * 64 + eo] = acc2[e][rg];
    }
}

// ---------------- kernel 4: tmpT[b][k][h*64+e] = (1/N) * sum_d dots_h[d,e] * Wq[h*64+d, k]
__global__ __launch_bounds__(256) void k_mmat(const float* __restrict__ partials,
                                              const float* __restrict__ wqkv,
                                              unsigned short* __restrict__ tmpT) {
  __shared__ float dl[4096];        // dots [d][e]
  __shared__ float wqls[64 * 256];  // Wq rows h*64+d: [d][k]
  const int bh = blockIdx.x, b = bh >> 3, h = bh & 7;
  const int t = threadIdx.x;
#pragma unroll
  for (int i = 0; i < 4; ++i) {
    int off = t * 16 + i * 4;
    f32x4 s = {0.f, 0.f, 0.f, 0.f};
    for (int c = 0; c < 16; ++c) {
      const size_t chunk = (size_t)(b * 16 + c) * 8 + h;
      f32x4 p = *(const f32x4*)(partials + chunk * 4096 + off);
      s += p;
    }
    *(f32x4*)&dl[off] = s;
  }
#pragma unroll
  for (int i = 0; i < 16; ++i) {
    int idx4 = i * 256 + t;           // float4 index into [64][256]
    int d = idx4 >> 6, c4 = idx4 & 63;
    *(f32x4*)&wqls[d * 256 + c4 * 4] =
        *(const f32x4*)(wqkv + (size_t)(h * 64 + d) * 256 + c4 * 4);
  }
  __syncthreads();
  const int k = t;
  const float scale = 1.0f / 8192.0f;
  float res[64];
  for (int e = 0; e < 64; ++e) {
    float s = 0.f;
#pragma unroll
    for (int d = 0; d < 64; ++d) s += dl[d * 64 + e] * wqls[d * 256 + k];
    res[e] = s * scale;
  }
  unsigned short* dstp = tmpT + (size_t)b * 131072 + (size_t)k * 512 + h * 64;
#pragma unroll
  for (int e8 = 0; e8 < 8; ++e8) {
    ushort8_t o;
#pragma unroll
    for (int j = 0; j < 8; ++j) o[j] = f2bf(res[e8 * 8 + j]);
    *(ushort8_t*)(dstp + e8 * 8) = o;
  }
}

// ---------------- kernel 5: P^T[b] = woutb(256o x 512he) @ tmpT[b](256k x 512he)
__global__ __launch_bounds__(256) void k_pmat(const unsigned short* __restrict__ woutb,
                                              const unsigned short* __restrict__ tmpT,
                                              unsigned short* __restrict__ pswz) {
  const int bid = blockIdx.x;
  const int b = bid >> 2, oq = (bid >> 1) & 1, kq = bid & 1;
  const int t = threadIdx.x, w = t >> 6, lane = t & 63, lr = lane & 15, lg = lane >> 4;
  const int wr = w >> 1, wc = w & 1;
  const int ob = oq * 128 + wr * 64, kb = kq * 128 + wc * 64;
  const unsigned short* tb = tmpT + (size_t)b * 131072;

  f32x4 acc[4][4];
#pragma unroll
  for (int mb = 0; mb < 4; ++mb)
#pragma unroll
    for (int nb = 0; nb < 4; ++nb) acc[mb][nb] = f32x4{0.f, 0.f, 0.f, 0.f};

  for (int ks = 0; ks < 16; ++ks) {
    bf16x8 a[4], bb[4];
#pragma unroll
    for (int mb = 0; mb < 4; ++mb)
      a[mb] = *(const bf16x8*)(woutb + (size_t)(ob + mb * 16 + lr) * 512 + ks * 32 + lg * 8);
#pragma unroll
    for (int nb = 0; nb < 4; ++nb)
      bb[nb] = *(const bf16x8*)(tb + (size_t)(kb + nb * 16 + lr) * 512 + ks * 32 + lg * 8);
#pragma unroll
    for (int mb = 0; mb < 4; ++mb)
#pragma unroll
      for (int nb = 0; nb < 4; ++nb) acc[mb][nb] = MFMA16(a[mb], bb[nb], acc[mb][nb]);
  }

  unsigned short* pb = pswz + (size_t)b * 65536;
#pragma unroll
  for (int mb = 0; mb < 4; ++mb)
#pragma unroll
    for (int nb = 0; nb < 4; ++nb)
#pragma unroll
      for (int rg = 0; rg < 4; ++rg) {
        int o = ob + mb * 16 + lg * 4 + rg;
        int k = kb + nb * 16 + lr;
        pb[(((k >> 5) * 16 + (o >> 4)) * 64 + (o & 15) + ((k >> 3) & 3) * 16) * 8 + (k & 7)] =
            f2bf(acc[mb][nb][rg]);
      }
}

// ---------------- kernel 6: out[b] = xb[b] @ P[b] + b_out  (M=8192, N=256, K=256)
// v3b: LDS-transposed coalesced f32 epilogue.
__global__ __launch_bounds__(512) void k_gemm2(const unsigned short* __restrict__ xb,
                                               const unsigned short* __restrict__ pswz,
                                               const float* __restrict__ bout,
                                               float* __restrict__ out) {
  __shared__ __align__(16) char smem[65536];
  unsigned short* As = (unsigned short*)smem;  // [2][128*64] = 32 KB (K-loop)
  float* lf = (float*)smem;                    // epilogue: [64][256] f32 = 64 KB

  const int b = blockIdx.x >> 6, mt = blockIdx.x & 63;
  const long m0 = (long)mt * 128;
  const int t = threadIdx.x, w = t >> 6, lane = t & 63, lr = lane & 15, lg = lane >> 4;
  const int wr = w >> 2, wc = w & 3;  // wave: 64 rows x 64 cols
  const unsigned short* qb = xb + ((size_t)b * 8192 + m0) * 256;
  const unsigned short* Mb = pswz + (size_t)b * 65536;
  const int srl = lane >> 3, sc = lane & 7;

#pragma unroll
  for (int i = 0; i < 2; ++i) {
    const int row = (i * 8 + w) * 8 + srl;  // 0..127
    gld_lds16(qb + (size_t)row * 256 + ((sc ^ (row & 7)) << 3),
              &As[(i * 8 + w) * 512]);
  }
  __syncthreads();

  f32x4 acc[4][4];
#pragma unroll
  for (int mb = 0; mb < 4; ++mb)
#pragma unroll
    for (int nb = 0; nb < 4; ++nb) acc[mb][nb] = f32x4{0.f, 0.f, 0.f, 0.f};

  for (int ks = 0; ks < 4; ++ks) {
    const int cur = ks & 1, nxt = cur ^ 1;
    if (ks < 3) {
      const int k0 = (ks + 1) * 64;
#pragma unroll
      for (int i = 0; i < 2; ++i) {
        const int row = (i * 8 + w) * 8 + srl;
        gld_lds16(qb + (size_t)row * 256 + k0 + ((sc ^ (row & 7)) << 3),
                  &As[nxt * 8192 + (i * 8 + w) * 512]);
      }
    }
    bf16x8 a[4][2], bfr[2][4];
#pragma unroll
    for (int mb = 0; mb < 4; ++mb) {
      const int R = wr * 64 + mb * 16 + lr;
#pragma unroll
      for (int kh = 0; kh < 2; ++kh)
        a[mb][kh] = *(const bf16x8*)&As[cur * 8192 + R * 64 + ((((kh << 2) + lg) ^ (R & 7)) << 3)];
    }
#pragma unroll
    for (int kh = 0; kh < 2; ++kh)
#pragma unroll
      for (int nb = 0; nb < 4; ++nb)
        bfr[kh][nb] = *(const bf16x8*)(Mb + ((((size_t)ks * 2 + kh) * 16 + wc * 4 + nb) * 64 + lane) * 8);
#pragma unroll
    for (int mb = 0; mb < 4; ++mb)
#pragma unroll
      for (int nb = 0; nb < 4; ++nb)
#pragma unroll
        for (int kh = 0; kh < 2; ++kh)
          acc[mb][nb] = MFMA16(a[mb][kh], bfr[kh][nb], acc[mb][nb]);
    __syncthreads();  // also protects lf overlay reuse
  }

  // ---- epilogue: 2 passes of 64 rows through LDS; coalesced float4 stores + bias
#pragma unroll
  for (int p = 0; p < 2; ++p) {
    if (wr == p) {
#pragma unroll
      for (int mb = 0; mb < 4; ++mb)
#pragma unroll
        for (int nb = 0; nb < 4; ++nb)
#pragma unroll
          for (int rg = 0; rg < 4; ++rg)
            lf[(mb * 16 + lg * 4 + rg) * 256 + wc * 64 + nb * 16 + lr] = acc[mb][nb][rg];
    }
    __syncthreads();
#pragma unroll
    for (int i = 0; i < 8; ++i) {
      const int idx = i * 512 + t;        // 4096 float4 chunks = 64 rows x 64 chunks
      const int r = idx >> 6, c4 = idx & 63;
      f32x4 v = *(f32x4*)&lf[r * 256 + c4 * 4];
      f32x4 bo4 = *(const f32x4*)(bout + c4 * 4);
      v += bo4;
      *(f32x4*)(out + ((size_t)b * 8192 + m0 + p * 64 + r) * 256 + c4 * 4) = v;
    }
    __syncthreads();
  }
}

extern "C" void kernel_launch(void* const* d_in, const int* in_sizes, int n_in,
                              void* d_out, int out_size, void* d_ws, size_t ws_size,
                              hipStream_t stream) {
  const float* x    = (const float*)d_in[0];  // [8,8192,256]
  const float* wqkv = (const float*)d_in[1];  // [1536,256]
  const float* wout = (const float*)d_in[2];  // [256,512]
  const float* bout = (const float*)d_in[3];  // [256]
  float* out = (float*)d_out;                 // [8,8192,256] f32

  char* ws = (char*)d_ws;
  unsigned short* xb = (unsigned short*)ws;                   // 65536*256 bf16 = 32 MB
  size_t off = (size_t)65536 * 256 * 2;
  unsigned short* wqb = (unsigned short*)(ws + off);          // 1536*256 bf16
  off += (size_t)1536 * 256 * 2;
  unsigned short* woutb = (unsigned short*)(ws + off);        // 256*512 bf16
  off += (size_t)256 * 512 * 2;
  float* partials = (float*)(ws + off);                       // 1024*4096 f32 = 16 MB
  off += (size_t)1024 * 4096 * 4;
  unsigned short* tmpT = (unsigned short*)(ws + off);         // 8*256*512 bf16 = 2 MB
  off += (size_t)8 * 131072 * 2;
  unsigned short* pswz = (unsigned short*)(ws + off);         // 8*256*256 bf16 = 1 MB
  off += (size_t)8 * 65536 * 2;

  k_conv<<<4096, 256, 0, stream>>>(x, wqkv, wout, xb, wqb, woutb);
  k_fused<<<1024, 512, 0, stream>>>(xb, wqb, partials);
  k_mmat<<<64, 256, 0, stream>>>(partials, wqkv, tmpT);
  k_pmat<<<32, 256, 0, stream>>>(woutb, tmpT, pswz);
  k_gemm2<<<512, 512, 0, stream>>>(xb, pswz, bout, out);
}

// Round 16
// 163.062 us; speedup vs baseline: 1.1093x; 1.1093x over previous
//
#include <hip/hip_runtime.h>
#include <hip/hip_bf16.h>
#include <stdint.h>

typedef __attribute__((ext_vector_type(8))) __bf16 bf16x8;
typedef __attribute__((ext_vector_type(8))) unsigned short ushort8_t;
typedef __attribute__((ext_vector_type(4))) unsigned short ushort4_t;
typedef __attribute__((ext_vector_type(4))) float f32x4;

#define MFMA16(a, b, c) __builtin_amdgcn_mfma_f32_16x16x32_bf16((a), (b), (c), 0, 0, 0)

static __device__ __forceinline__ unsigned short f2bf(float f) {
  union { float f; unsigned u; } v; v.f = f;
  unsigned r = v.u + 0x7fffu + ((v.u >> 16) & 1u);  // RNE
  return (unsigned short)(r >> 16);
}
static __device__ __forceinline__ float bf2f(unsigned short u) {
  union { unsigned u; float f; } v; v.u = ((unsigned)u) << 16; return v.f;
}

static __device__ __forceinline__ void gld_lds16(const void* g, void* l) {
  __builtin_amdgcn_global_load_lds((const __attribute__((address_space(1))) void*)g,
                                   (__attribute__((address_space(3))) void*)l, 16, 0, 0);
}

// ---------------- kernel 0: convert x, w_qkv, w_out f32 -> bf16 (grid-stride, one launch)
__global__ __launch_bounds__(256) void k_conv(const float* __restrict__ x,
                                              const float* __restrict__ wqkv,
                                              const float* __restrict__ wout,
                                              unsigned short* __restrict__ xb,
                                              unsigned short* __restrict__ wqb,
                                              unsigned short* __restrict__ woutb) {
  const size_t NX = 4194304;   // 65536*256/4
  const size_t NW = 98304;     // 1536*256/4
  const size_t NO = 32768;     // 256*512/4
  const size_t stride = (size_t)gridDim.x * 256;
  for (size_t i4 = (size_t)blockIdx.x * 256 + threadIdx.x; i4 < NX + NW + NO; i4 += stride) {
    const float* src; unsigned short* dst; size_t off;
    if (i4 < NX)           { src = x;    dst = xb;    off = i4; }
    else if (i4 < NX + NW) { src = wqkv; dst = wqb;   off = i4 - NX; }
    else                   { src = wout; dst = woutb; off = i4 - NX - NW; }
    float4 v = ((const float4*)src)[off];
    ushort4_t o = { f2bf(v.x), f2bf(v.y), f2bf(v.z), f2bf(v.w) };
    *(ushort4_t*)(dst + off * 4) = o;
  }
}

// ---------------- kernel 1: FUSED K/V projection + instance-norm + dots.
// Round-8 dataflow verbatim; ONE isolated diff: overlay is XOR-swizzled [2][64][64]
// (verified addressing, rounds 12/13/15) instead of [64][72] — kills bank conflicts
// on dots reads. Same footprint (2x16 KB in As region), same barriers, same staging.
__global__ __launch_bounds__(512) void k_fused(const unsigned short* __restrict__ xb,
                                               const unsigned short* __restrict__ wqb,
                                               float* __restrict__ partials) {
  __shared__ __align__(16) char smem[65536];
  unsigned short* As = (unsigned short*)smem;            // [2][128*64] = 32 KB
  unsigned short* Bs = (unsigned short*)(smem + 32768);  // [2][128*64] = 32 KB
  unsigned short* kt = (unsigned short*)smem;            // overlay [2][64][64] swz, 16 KB
  unsigned short* vt = (unsigned short*)(smem + 16384);  // overlay [2][64][64] swz, 16 KB

  const int t = threadIdx.x;
  const int w = t >> 6, lane = t & 63, lr = lane & 15, lg = lane >> 4;
  const int wr = w >> 1, wc = w & 1;    // GEMM: 32-row strip wr, tensor wc (0=K,1=V)
  const int dblk = w >> 1, ep = w & 1;  // dots role: d-block, e-half

  // XCD-chunked swizzle: 1024 blocks = 128 mgroups x 8 heads; XCD owns 16 mgroups
  const int id = blockIdx.x;
  const int nid = (id & 7) * 128 + (id >> 3);
  const int mg = nid >> 3, h = nid & 7;

  const int srl = lane >> 3, sc = lane & 7;
  const int swz = (sc ^ srl) << 3;      // staging row%8 == srl

  const unsigned short* bptr[2];
  int aoff[2];
#pragma unroll
  for (int i = 0; i < 2; ++i) {
    const int br = (w * 2 + i) * 8 + srl;   // 0..127
    const int grow = (br < 64) ? (512 + h * 64 + br) : (1024 + h * 64 + (br - 64));
    bptr[i] = wqb + (size_t)grow * 256 + swz;
    aoff[i] = br * 256 + swz;
  }

  f32x4 acc2[2] = {f32x4{0.f, 0.f, 0.f, 0.f}, f32x4{0.f, 0.f, 0.f, 0.f}};

  for (int mi = 0; mi < 4; ++mi) {
    const long m0 = ((long)mg * 4 + mi) * 128;
    const unsigned short* am = xb + (size_t)m0 * 256;

    // prologue: stage K-tile 0 into buf0
#pragma unroll
    for (int i = 0; i < 2; ++i) {
      gld_lds16(am + aoff[i], &As[(w * 2 + i) * 512]);
      gld_lds16(bptr[i],      &Bs[(w * 2 + i) * 512]);
    }
    __syncthreads();

    f32x4 acc[2][4];
#pragma unroll
    for (int mb = 0; mb < 2; ++mb)
#pragma unroll
      for (int nb = 0; nb < 4; ++nb) acc[mb][nb] = f32x4{0.f, 0.f, 0.f, 0.f};

    for (int ktt = 0; ktt < 4; ++ktt) {
      const int cur = ktt & 1, nxt = cur ^ 1;
      if (ktt < 3) {
        const int k0 = (ktt + 1) * 64;
#pragma unroll
        for (int i = 0; i < 2; ++i) {
          gld_lds16(am + aoff[i] + k0, &As[nxt * 8192 + (w * 2 + i) * 512]);
          gld_lds16(bptr[i] + k0,      &Bs[nxt * 8192 + (w * 2 + i) * 512]);
        }
      }
      bf16x8 a[2][2], b[4][2];
#pragma unroll
      for (int mb = 0; mb < 2; ++mb) {
        const int R = wr * 32 + mb * 16 + lr;
#pragma unroll
        for (int kh = 0; kh < 2; ++kh)
          a[mb][kh] = *(const bf16x8*)&As[cur * 8192 + R * 64 + ((((kh << 2) + lg) ^ (R & 7)) << 3)];
      }
#pragma unroll
      for (int nb = 0; nb < 4; ++nb) {
        const int E = wc * 64 + nb * 16 + lr;
#pragma unroll
        for (int kh = 0; kh < 2; ++kh)
          b[nb][kh] = *(const bf16x8*)&Bs[cur * 8192 + E * 64 + ((((kh << 2) + lg) ^ (E & 7)) << 3)];
      }
#pragma unroll
      for (int mb = 0; mb < 2; ++mb)
#pragma unroll
        for (int nb = 0; nb < 4; ++nb)
#pragma unroll
          for (int kh = 0; kh < 2; ++kh)
            acc[mb][nb] = MFMA16(a[mb][kh], b[nb][kh], acc[mb][nb]);
      __syncthreads();
    }

    // ---- instance-norm in-register (full 64 d per wave), swizzled overlay write
    unsigned short* dst = (wc == 0) ? kt : vt;
#pragma unroll
    for (int mb = 0; mb < 2; ++mb) {
#pragma unroll
      for (int rg = 0; rg < 4; ++rg) {
        float s1 = acc[mb][0][rg] + acc[mb][1][rg] + acc[mb][2][rg] + acc[mb][3][rg];
        float s2 = acc[mb][0][rg] * acc[mb][0][rg] + acc[mb][1][rg] * acc[mb][1][rg] +
                   acc[mb][2][rg] * acc[mb][2][rg] + acc[mb][3][rg] * acc[mb][3][rg];
        s1 += __shfl_xor(s1, 1); s2 += __shfl_xor(s2, 1);
        s1 += __shfl_xor(s1, 2); s2 += __shfl_xor(s2, 2);
        s1 += __shfl_xor(s1, 4); s2 += __shfl_xor(s2, 4);
        s1 += __shfl_xor(s1, 8); s2 += __shfl_xor(s2, 8);
        const float mean = s1 * (1.f / 64.f);
        const float rs = rsqrtf(s2 * (1.f / 64.f) - mean * mean + 1e-5f);
        const int n = wr * 32 + mb * 16 + lg * 4 + rg;
        const int cn = n >> 6, nn = n & 63;
        const int cc = nn >> 3, cj = nn & 7;
#pragma unroll
        for (int nb = 0; nb < 4; ++nb) {
          const int d = nb * 16 + lr;
          dst[cn * 4096 + d * 64 + ((cc ^ (d & 7)) << 3) + cj] =
              f2bf((acc[mb][nb][rg] - mean) * rs);
        }
      }
    }
    __syncthreads();

    // ---- dots: D[d,e] += sum_n K^[n,d] V^[n,e] (swizzled overlay reads)
#pragma unroll
    for (int cn = 0; cn < 2; ++cn) {
#pragma unroll
      for (int ns = 0; ns < 64; ns += 32) {
        const int cA = (ns >> 3) + lg;
        const int dd = dblk * 16 + lr;
        bf16x8 af = *(const bf16x8*)&kt[cn * 4096 + dd * 64 + ((cA ^ (dd & 7)) << 3)];
#pragma unroll
        for (int e = 0; e < 2; ++e) {
          const int ee = (ep * 2 + e) * 16 + lr;
          bf16x8 bv = *(const bf16x8*)&vt[cn * 4096 + ee * 64 + ((cA ^ (ee & 7)) << 3)];
          acc2[e] = MFMA16(af, bv, acc2[e]);
        }
      }
    }
    __syncthreads();  // overlay reads done before next m-tile staging
  }

  float* pb = partials + ((size_t)mg * 8 + h) * 4096;
#pragma unroll
  for (int e = 0; e < 2; ++e)
#pragma unroll
    for (int rg = 0; rg < 4; ++rg) {
      const int d = dblk * 16 + lg * 4 + rg;
      const int eo = (ep * 2 + e) * 16 + lr;
      pb[d * 64 + eo] = acc2[e][rg];
    }
}

// ---------------- kernel 4: tmpT[b][k][h*64+e] = (1/N) * sum_d dots_h[d,e] * Wq[h*64+d, k]
__global__ __launch_bounds__(256) void k_mmat(const float* __restrict__ partials,
                                              const float* __restrict__ wqkv,
                                              unsigned short* __restrict__ tmpT) {
  __shared__ float dl[4096];        // dots [d][e]
  __shared__ float wqls[64 * 256];  // Wq rows h*64+d: [d][k]
  const int bh = blockIdx.x, b = bh >> 3, h = bh & 7;
  const int t = threadIdx.x;
#pragma unroll
  for (int i = 0; i < 4; ++i) {
    int off = t * 16 + i * 4;
    f32x4 s = {0.f, 0.f, 0.f, 0.f};
    for (int c = 0; c < 16; ++c) {
      const size_t chunk = (size_t)(b * 16 + c) * 8 + h;
      f32x4 p = *(const f32x4*)(partials + chunk * 4096 + off);
      s += p;
    }
    *(f32x4*)&dl[off] = s;
  }
#pragma unroll
  for (int i = 0; i < 16; ++i) {
    int idx4 = i * 256 + t;           // float4 index into [64][256]
    int d = idx4 >> 6, c4 = idx4 & 63;
    *(f32x4*)&wqls[d * 256 + c4 * 4] =
        *(const f32x4*)(wqkv + (size_t)(h * 64 + d) * 256 + c4 * 4);
  }
  __syncthreads();
  const int k = t;
  const float scale = 1.0f / 8192.0f;
  float res[64];
  for (int e = 0; e < 64; ++e) {
    float s = 0.f;
#pragma unroll
    for (int d = 0; d < 64; ++d) s += dl[d * 64 + e] * wqls[d * 256 + k];
    res[e] = s * scale;
  }
  unsigned short* dstp = tmpT + (size_t)b * 131072 + (size_t)k * 512 + h * 64;
#pragma unroll
  for (int e8 = 0; e8 < 8; ++e8) {
    ushort8_t o;
#pragma unroll
    for (int j = 0; j < 8; ++j) o[j] = f2bf(res[e8 * 8 + j]);
    *(ushort8_t*)(dstp + e8 * 8) = o;
  }
}

// ---------------- kernel 5: P^T[b] = woutb(256o x 512he) @ tmpT[b](256k x 512he)
__global__ __launch_bounds__(256) void k_pmat(const unsigned short* __restrict__ woutb,
                                              const unsigned short* __restrict__ tmpT,
                                              unsigned short* __restrict__ pswz) {
  const int bid = blockIdx.x;
  const int b = bid >> 2, oq = (bid >> 1) & 1, kq = bid & 1;
  const int t = threadIdx.x, w = t >> 6, lane = t & 63, lr = lane & 15, lg = lane >> 4;
  const int wr = w >> 1, wc = w & 1;
  const int ob = oq * 128 + wr * 64, kb = kq * 128 + wc * 64;
  const unsigned short* tb = tmpT + (size_t)b * 131072;

  f32x4 acc[4][4];
#pragma unroll
  for (int mb = 0; mb < 4; ++mb)
#pragma unroll
    for (int nb = 0; nb < 4; ++nb) acc[mb][nb] = f32x4{0.f, 0.f, 0.f, 0.f};

  for (int ks = 0; ks < 16; ++ks) {
    bf16x8 a[4], bb[4];
#pragma unroll
    for (int mb = 0; mb < 4; ++mb)
      a[mb] = *(const bf16x8*)(woutb + (size_t)(ob + mb * 16 + lr) * 512 + ks * 32 + lg * 8);
#pragma unroll
    for (int nb = 0; nb < 4; ++nb)
      bb[nb] = *(const bf16x8*)(tb + (size_t)(kb + nb * 16 + lr) * 512 + ks * 32 + lg * 8);
#pragma unroll
    for (int mb = 0; mb < 4; ++mb)
#pragma unroll
      for (int nb = 0; nb < 4; ++nb) acc[mb][nb] = MFMA16(a[mb], bb[nb], acc[mb][nb]);
  }

  unsigned short* pb = pswz + (size_t)b * 65536;
#pragma unroll
  for (int mb = 0; mb < 4; ++mb)
#pragma unroll
    for (int nb = 0; nb < 4; ++nb)
#pragma unroll
      for (int rg = 0; rg < 4; ++rg) {
        int o = ob + mb * 16 + lg * 4 + rg;
        int k = kb + nb * 16 + lr;
        pb[(((k >> 5) * 16 + (o >> 4)) * 64 + (o & 15) + ((k >> 3) & 3) * 16) * 8 + (k & 7)] =
            f2bf(acc[mb][nb][rg]);
      }
}

// ---------------- kernel 6: out[b] = xb[b] @ P[b] + b_out  (M=8192, N=256, K=256)
// v3b: LDS-transposed coalesced f32 epilogue.
__global__ __launch_bounds__(512) void k_gemm2(const unsigned short* __restrict__ xb,
                                               const unsigned short* __restrict__ pswz,
                                               const float* __restrict__ bout,
                                               float* __restrict__ out) {
  __shared__ __align__(16) char smem[65536];
  unsigned short* As = (unsigned short*)smem;  // [2][128*64] = 32 KB (K-loop)
  float* lf = (float*)smem;                    // epilogue: [64][256] f32 = 64 KB

  const int b = blockIdx.x >> 6, mt = blockIdx.x & 63;
  const long m0 = (long)mt * 128;
  const int t = threadIdx.x, w = t >> 6, lane = t & 63, lr = lane & 15, lg = lane >> 4;
  const int wr = w >> 2, wc = w & 3;  // wave: 64 rows x 64 cols
  const unsigned short* qb = xb + ((size_t)b * 8192 + m0) * 256;
  const unsigned short* Mb = pswz + (size_t)b * 65536;
  const int srl = lane >> 3, sc = lane & 7;

#pragma unroll
  for (int i = 0; i < 2; ++i) {
    const int row = (i * 8 + w) * 8 + srl;  // 0..127
    gld_lds16(qb + (size_t)row * 256 + ((sc ^ (row & 7)) << 3),
              &As[(i * 8 + w) * 512]);
  }
  __syncthreads();

  f32x4 acc[4][4];
#pragma unroll
  for (int mb = 0; mb < 4; ++mb)
#pragma unroll
    for (int nb = 0; nb < 4; ++nb) acc[mb][nb] = f32x4{0.f, 0.f, 0.f, 0.f};

  for (int ks = 0; ks < 4; ++ks) {
    const int cur = ks & 1, nxt = cur ^ 1;
    if (ks < 3) {
      const int k0 = (ks + 1) * 64;
#pragma unroll
      for (int i = 0; i < 2; ++i) {
        const int row = (i * 8 + w) * 8 + srl;
        gld_lds16(qb + (size_t)row * 256 + k0 + ((sc ^ (row & 7)) << 3),
                  &As[nxt * 8192 + (i * 8 + w) * 512]);
      }
    }
    bf16x8 a[4][2], bfr[2][4];
#pragma unroll
    for (int mb = 0; mb < 4; ++mb) {
      const int R = wr * 64 + mb * 16 + lr;
#pragma unroll
      for (int kh = 0; kh < 2; ++kh)
        a[mb][kh] = *(const bf16x8*)&As[cur * 8192 + R * 64 + ((((kh << 2) + lg) ^ (R & 7)) << 3)];
    }
#pragma unroll
    for (int kh = 0; kh < 2; ++kh)
#pragma unroll
      for (int nb = 0; nb < 4; ++nb)
        bfr[kh][nb] = *(const bf16x8*)(Mb + ((((size_t)ks * 2 + kh) * 16 + wc * 4 + nb) * 64 + lane) * 8);
#pragma unroll
    for (int mb = 0; mb < 4; ++mb)
#pragma unroll
      for (int nb = 0; nb < 4; ++nb)
#pragma unroll
        for (int kh = 0; kh < 2; ++kh)
          acc[mb][nb] = MFMA16(a[mb][kh], bfr[kh][nb], acc[mb][nb]);
    __syncthreads();  // also protects lf overlay reuse
  }

  // ---- epilogue: 2 passes of 64 rows through LDS; coalesced float4 stores + bias
#pragma unroll
  for (int p = 0; p < 2; ++p) {
    if (wr == p) {
#pragma unroll
      for (int mb = 0; mb < 4; ++mb)
#pragma unroll
        for (int nb = 0; nb < 4; ++nb)
#pragma unroll
          for (int rg = 0; rg < 4; ++rg)
            lf[(mb * 16 + lg * 4 + rg) * 256 + wc * 64 + nb * 16 + lr] = acc[mb][nb][rg];
    }
    __syncthreads();
#pragma unroll
    for (int i = 0; i < 8; ++i) {
      const int idx = i * 512 + t;        // 4096 float4 chunks = 64 rows x 64 chunks
      const int r = idx >> 6, c4 = idx & 63;
      f32x4 v = *(f32x4*)&lf[r * 256 + c4 * 4];
      f32x4 bo4 = *(const f32x4*)(bout + c4 * 4);
      v += bo4;
      *(f32x4*)(out + ((size_t)b * 8192 + m0 + p * 64 + r) * 256 + c4 * 4) = v;
    }
    __syncthreads();
  }
}

extern "C" void kernel_launch(void* const* d_in, const int* in_sizes, int n_in,
                              void* d_out, int out_size, void* d_ws, size_t ws_size,
                              hipStream_t stream) {
  const float* x    = (const float*)d_in[0];  // [8,8192,256]
  const float* wqkv = (const float*)d_in[1];  // [1536,256]
  const float* wout = (const float*)d_in[2];  // [256,512]
  const float* bout = (const float*)d_in[3];  // [256]
  float* out = (float*)d_out;                 // [8,8192,256] f32

  char* ws = (char*)d_ws;
  unsigned short* xb = (unsigned short*)ws;                   // 65536*256 bf16 = 32 MB
  size_t off = (size_t)65536 * 256 * 2;
  unsigned short* wqb = (unsigned short*)(ws + off);          // 1536*256 bf16
  off += (size_t)1536 * 256 * 2;
  unsigned short* woutb = (unsigned short*)(ws + off);        // 256*512 bf16
  off += (size_t)256 * 512 * 2;
  float* partials = (float*)(ws + off);                       // 1024*4096 f32 = 16 MB
  off += (size_t)1024 * 4096 * 4;
  unsigned short* tmpT = (unsigned short*)(ws + off);         // 8*256*512 bf16 = 2 MB
  off += (size_t)8 * 131072 * 2;
  unsigned short* pswz = (unsigned short*)(ws + off);         // 8*256*256 bf16 = 1 MB
  off += (size_t)8 * 65536 * 2;

  k_conv<<<4096, 256, 0, stream>>>(x, wqkv, wout, xb, wqb, woutb);
  k_fused<<<1024, 512, 0, stream>>>(xb, wqb, partials);
  k_mmat<<<64, 256, 0, stream>>>(partials, wqkv, tmpT);
  k_pmat<<<32, 256, 0, stream>>>(woutb, tmpT, pswz);
  k_gemm2<<<512, 512, 0, stream>>>(xb, pswz, bout, out);
}